// Round 9
// baseline (160.489 us; speedup 1.0000x reference)
//
#include <hip/hip_runtime.h>
#include <hip/hip_bf16.h>
#include <math.h>

// Problem constants (fixed by setup_inputs)
#define NN   5570
#define BB   16
#define CIN  35
#define MPAD 5632      // NN padded to 88*64
#define NCHUNK 176     // MPAD/32  (k-chunks of 32)
#define OUTER 22       // split-K slices (blockIdx.y); 8 chunks = 256 k each
#define CPS  8         // chunks per slice

// workspace layout (float offsets); total 9,043,840 floats ~= 36.2 MB
#define OFF_RSUM 0                          // [OUTER][MPAD] fp32 = 123904
#define OFF_G0C  123904                     // [BB][NN][4] fp32 = 356480
#define OFF_PGP  480384                     // [OUTER][BB][NN][4] fp32 = 7842560
#define OFF_GTF  8322944                    // gtf bf16 [NCHUNK][BB][64][8]

typedef __attribute__((ext_vector_type(8))) short  short8;
typedef __attribute__((ext_vector_type(4))) float  floatx4;

static __device__ inline ushort f2bf(float f) {
    union { __hip_bfloat16 h; ushort u; } cv;
    cv.h = __float2bfloat16(f);
    return cv.u;
}

// ---------------------------------------------------------------------------
// Kernel G: per (b, m):
//   a0[dj] = sum_c x[b,m,c]*w_k0[d,c,j];  g0c[b][m][j] = sum_d E[m,d]*a0[dj]
//   a1[dj] = sum_c x[b,m,c]*w_k1[d,c,j] -> gtf bf16 in MFMA-B-fragment order:
//       gtf[((ck*16 + b)*64 + quad*16 + dj)*8 + u],  m = ck*32 + quad*8 + u
// Writes go through an LDS transpose so global stores are coalesced short8.
// ---------------------------------------------------------------------------
__global__ __launch_bounds__(256)
void kg_g(const float* __restrict__ x, const float* __restrict__ e,
          const float* __restrict__ wg, const float* __restrict__ wu,
          float* __restrict__ g0c, ushort* __restrict__ gtf) {
    __shared__ float xs[256 * CIN];
    __shared__ float wl[8 * CIN * 4];    // [(k*4+d)*35 + c]*4 + j
    __shared__ ushort ls[256 * 17];      // staged a1, row stride 17 (pad)
    int tid = threadIdx.x;
    int b   = blockIdx.y;
    int m0  = blockIdx.x * 256;

    for (int i = tid; i < 8 * CIN * 4; i += 256) {
        int j = i & 3, rest = i >> 2;
        int c = rest % CIN, kd = rest / CIN;
        int k = kd >> 2, d = kd & 3;
        float v;
        if (j < 2) v = wg[((d * 2 + k) * 37 + c) * 4 + 2 + j];
        else       v = wu[((d * 2 + k) * 37 + c) * 2 + (j - 2)];
        wl[i] = v;
    }
    int rows = NN - m0; if (rows > 256) rows = 256; if (rows < 0) rows = 0;
    const float* xsrc = x + ((size_t)b * NN + m0) * CIN;
    for (int i = tid; i < rows * CIN; i += 256) xs[i] = xsrc[i];
    __syncthreads();

    int m = m0 + tid;
    float a1[16];
    #pragma unroll
    for (int i = 0; i < 16; ++i) a1[i] = 0.f;

    if (m < NN) {
        float a0[16];
        #pragma unroll
        for (int i = 0; i < 16; ++i) a0[i] = 0.f;
        for (int c = 0; c < CIN; ++c) {
            float xa = xs[tid * CIN + c];
            #pragma unroll
            for (int kd = 0; kd < 8; ++kd) {
                const float4 w = *(const float4*)&wl[(kd * CIN + c) * 4];
                const int d4 = (kd & 3) * 4;
                if (kd < 4) {
                    a0[d4+0] += xa*w.x; a0[d4+1] += xa*w.y;
                    a0[d4+2] += xa*w.z; a0[d4+3] += xa*w.w;
                } else {
                    a1[d4+0] += xa*w.x; a1[d4+1] += xa*w.y;
                    a1[d4+2] += xa*w.z; a1[d4+3] += xa*w.w;
                }
            }
        }
        // fold E-contraction for k=0 term: p0[j] = sum_d E[m,d]*a0[d*4+j]
        float4 em4 = ((const float4*)e)[m];
        float p0[4];
        #pragma unroll
        for (int j = 0; j < 4; ++j)
            p0[j] = em4.x*a0[j] + em4.y*a0[4+j] + em4.z*a0[8+j] + em4.w*a0[12+j];
        ((float4*)g0c)[(size_t)b * NN + m] = make_float4(p0[0], p0[1], p0[2], p0[3]);
    }

    // stage a1 -> LDS [m_local][dj] (stride 17)
    #pragma unroll
    for (int dj = 0; dj < 16; ++dj) ls[tid * 17 + dj] = f2bf(a1[dj]);
    __syncthreads();

    // coalesced write-out: wave w handles local chunks {2w, 2w+1}
    const int wave = tid >> 6, lane = tid & 63;
    const int qo = lane >> 4, dj = lane & 15;
    #pragma unroll
    for (int i = 0; i < 2; ++i) {
        const int lc = wave * 2 + i;
        const int ck = blockIdx.x * 8 + lc;
        short8 v;
        #pragma unroll
        for (int u = 0; u < 8; ++u)
            v[u] = (short)ls[(lc * 32 + qo * 8 + u) * 17 + dj];
        *(short8*)&gtf[((size_t)(ck * 16 + b)) * 512 + lane * 8] = v;
    }
}

// ---------------------------------------------------------------------------
// Kernel B (fused score-gen + MFMA, LDS double-buffered B via global_load_lds):
//   PG contribution over slice s: sum_m exp(relu(E_n.E_m)) * G1[m][col]
//   rsums[s][n] = per-slice row sum of scores (no atomics)
// R9 = R8's traffic cut x R6's wave count:
//  - R6 counted-vmcnt pipeline (CONFIRMED -6us): issue chunk st+1 ->
//    s_waitcnt vmcnt(4) (waits ONLY chunk st; st+1 in flight ACROSS the
//    barrier) -> compute -> raw s_barrier (no drain).
//  - 2 row-tiles per wave (R8): every B-frag ds_read feeds 2 MFMAs, every
//    esl read feeds 2 dots -> LDS ceiling 29 -> 14.6us.
//  - OUTER=22/CPS=8: grid 44x22 = 968 blocks (3.78/CU demand) restores the
//    wave concurrency R8 lost (R8: 484 blocks -> 8 waves/CU -> 35% pipe
//    efficiency; R6: 15 waves/CU -> 76%).
//  - __launch_bounds__(256,3): 12 waves/CU target (VGPR<=168; acc=128).
// Cross-round law: kb efficiency tracks waves/CU; ceiling tracks traffic.
// This is the first variant cutting traffic at PRESERVED wave count.
// esl stored XOR-swizzled (slot = i ^ ((i>>3)&7)) - measured-neutral, kept.
// NOTE (R1): counter-fused final epilogue FAILED correctness cross-XCD.
// NOTE (R7): cross-XCD atomicAdd accumulation ALSO failed (absmax 0.58).
//            ONLY kernel-boundary plain-store dataflow is safe here.
// NOTE (R4): B-frags direct from L2 regressed (87us) - raw L2 latency.
// NOTE (R5): OUTER=22 with drain-barriers + 1936 blocks regressed; the
//            drain is gone (R6) and blocks stay at 968 here.
// ---------------------------------------------------------------------------
static __device__ inline void load_chunk(const ushort* __restrict__ gsrc,
                                         ushort* ldst, int tid, int wave) {
    #pragma unroll
    for (int i = 0; i < 4; ++i) {
        const ushort* g = gsrc + (size_t)(i * 256 + tid) * 8;
        ushort* l = ldst + (size_t)(i * 256 + wave * 64) * 8;  // wave-uniform base
        __builtin_amdgcn_global_load_lds(
            (const __attribute__((address_space(1))) unsigned int*)g,
            (__attribute__((address_space(3))) unsigned int*)l, 16, 0, 0);
    }
}

template <bool CHECK>
__device__ __forceinline__ void kb_main(const float4* __restrict__ esl,
                                        const ushort* __restrict__ gsl,
                                        ushort (*sbuf)[8192],
                                        const float4 en0, const float4 en1,
                                        int k0m, int tid, int wave, int lane,
                                        int quad, floatx4 (&acc)[2][16],
                                        float& rowsum0, float& rowsum1) {
    #pragma unroll 2
    for (int st = 0; st < CPS; ++st) {
        // [A] issue next chunk, [B] wait ONLY for chunk st (counted, not 0)
        if (st + 1 < CPS) {
            load_chunk(gsl + (size_t)(st + 1) * 8192, sbuf[(st + 1) & 1], tid, wave);
            asm volatile("s_waitcnt vmcnt(4)" ::: "memory");
        } else {
            asm volatile("s_waitcnt vmcnt(0)" ::: "memory");
        }

        // scores: lane holds A0[wr0+l15][quad*8+u], A1[wr0+16+l15][quad*8+u]
        short8 af0, af1;
        const int stq = st * 32 + quad * 8;
        const int ux  = (st * 4 + quad) & 7;   // esl XOR-swizzle key
        #pragma unroll
        for (int u = 0; u < 8; ++u) {
            float4 em = esl[stq + (u ^ ux)];   // swizzled slot holds row stq+u
            float d0 = en0.x*em.x + en0.y*em.y + en0.z*em.z + en0.w*em.w;
            float d1 = en1.x*em.x + en1.y*em.y + en1.z*em.z + en1.w*em.w;
            float s0 = __expf(fmaxf(d0, 0.f));
            float s1 = __expf(fmaxf(d1, 0.f));
            if (CHECK && (k0m + stq + u >= NN)) { s0 = 0.f; s1 = 0.f; }
            rowsum0 += s0; rowsum1 += s1;
            af0[u] = (short)f2bf(s0);
            af1[u] = (short)f2bf(s1);
        }

        const ushort* bb = &sbuf[st & 1][lane * 8];
        #pragma unroll
        for (int ct = 0; ct < 16; ++ct) {
            short8 bf = *(const short8*)&bb[ct * 512];   // read once...
            acc[0][ct] = __builtin_amdgcn_mfma_f32_16x16x32_bf16(af0, bf, acc[0][ct], 0, 0, 0);
            acc[1][ct] = __builtin_amdgcn_mfma_f32_16x16x32_bf16(af1, bf, acc[1][ct], 0, 0, 0);  // ...use twice
        }

        // [D] raw barrier, NO vmcnt drain: chunk st+1 stays in flight.
        // Seals buf[st&1] reads before step st+1 overwrites it.
        __builtin_amdgcn_s_barrier();
    }
}

__global__ __launch_bounds__(256, 3)
void kb_pg(const float* __restrict__ e, const ushort* __restrict__ gtf,
           float* __restrict__ pgp, float* __restrict__ rsums) {
    __shared__ ushort sbuf[2][8192];     // double-buffered B chunk, 32 KB
    __shared__ float4 esl[CPS * 32];     // slice's E rows (XOR-swizzled), 4 KB
    const int tid  = threadIdx.x;
    const int wave = tid >> 6;
    const int lane = tid & 63;
    const int l15  = lane & 15;
    const int quad = lane >> 4;
    const int wr0  = (blockIdx.x * 4 + wave) * 32;   // first row of this wave
    const int s    = blockIdx.y;
    const int k0m  = s * (CPS * 32);     // first m of slice
    const float4* E4 = (const float4*)e;

    // stage slice E rows (swizzled: slot i^((i>>3)&7) holds row i) + first chunk
    for (int i = tid; i < CPS * 32; i += 256) {
        int m = k0m + i;
        esl[i ^ ((i >> 3) & 7)] = (m < NN) ? E4[m] : make_float4(0.f, 0.f, 0.f, 0.f);
    }
    const ushort* gsl = gtf + (size_t)s * CPS * 8192;
    load_chunk(gsl, sbuf[0], tid, wave);

    const int nr0 = wr0 + l15, nr1 = wr0 + 16 + l15;
    const float4 en0 = E4[nr0 < NN ? nr0 : 0];
    const float4 en1 = E4[nr1 < NN ? nr1 : 0];

    floatx4 acc[2][16];
    #pragma unroll
    for (int t = 0; t < 2; ++t)
        #pragma unroll
        for (int i = 0; i < 16; ++i) acc[t][i] = (floatx4){0.f, 0.f, 0.f, 0.f};
    float rowsum0 = 0.f, rowsum1 = 0.f;

    __syncthreads();   // prologue sync: esl visible + chunk0 drained (once)

    if (k0m + CPS * 32 <= NN)
        kb_main<false>(esl, gsl, sbuf, en0, en1, k0m, tid, wave, lane, quad,
                       acc, rowsum0, rowsum1);
    else
        kb_main<true >(esl, gsl, sbuf, en0, en1, k0m, tid, wave, lane, quad,
                       acc, rowsum0, rowsum1);

    // rsums: row l15, partial per quad -> butterfly over quads, quad0 stores
    rowsum0 += __shfl_xor(rowsum0, 16);
    rowsum0 += __shfl_xor(rowsum0, 32);
    rowsum1 += __shfl_xor(rowsum1, 16);
    rowsum1 += __shfl_xor(rowsum1, 32);
    if (quad == 0) {
        rsums[(size_t)s * MPAD + nr0] = rowsum0;   // nr < MPAD always
        rsums[(size_t)s * MPAD + nr1] = rowsum1;
    }

    // epilogue per tile t: acc[t][ct][j] = D[n = wr0+t*16+quad*4+j][dj = l15]
    // contract dj = d*4+jj with E[n,d]: reduce over d via shfl_xor(4),(8)
    const int dsel = l15 >> 2, jj = l15 & 3;
    #pragma unroll
    for (int t = 0; t < 2; ++t) {
        const int nbase = wr0 + t * 16;
        float end[4];
        #pragma unroll
        for (int j = 0; j < 4; ++j) {
            int n = nbase + quad * 4 + j;
            end[j] = (n < NN) ? e[n * 4 + dsel] : 0.f;
        }
        #pragma unroll
        for (int ct = 0; ct < 16; ++ct) {
            #pragma unroll
            for (int j = 0; j < 4; ++j) {
                float v = end[j] * acc[t][ct][j];
                v += __shfl_xor(v, 4);
                v += __shfl_xor(v, 8);
                int n = nbase + quad * 4 + j;
                if (l15 < 4 && n < NN)
                    pgp[(((size_t)s * BB + ct) * NN + n) * 4 + jj] = v;
            }
        }
    }
}

// ---------------------------------------------------------------------------
// Kernel E: tiny epilogue
// pre[j] = g0c[b][n][j] + (1/sum_s rsums[s][n]) * sum_s pgp[s][b][n][j]
//          + sum_d E[n,d]*bias[d][j]
// R=sigmoid(pre[0..1]), C=tanh(pre[2..3]), h=(1-R)*C, y = relu(h)@lin_w + lin_b
// ---------------------------------------------------------------------------
static __device__ inline float fsig(float x) {
    return 1.f / (1.f + __expf(-x));
}
static __device__ inline float ftanh(float x) {
    float t = __expf(fminf(2.f * x, 80.f));
    return (t - 1.f) / (t + 1.f);
}

__global__ __launch_bounds__(256)
void ke_out(const float* __restrict__ e, const float* __restrict__ rsums,
            const float* __restrict__ g0c, const float* __restrict__ pgp,
            const float* __restrict__ bg, const float* __restrict__ bu,
            const float* __restrict__ lw, const float* __restrict__ lb,
            float* __restrict__ out) {
    int n = blockIdx.x * 256 + threadIdx.x;
    int b = blockIdx.y;
    if (n >= NN) return;
    float4 ev = ((const float4*)e)[n];
    float ed[4] = {ev.x, ev.y, ev.z, ev.w};
    float den = 0.f;
    #pragma unroll
    for (int s = 0; s < OUTER; ++s) den += rsums[(size_t)s * MPAD + n];
    float rd = 1.f / den;

    float pgf[4] = {0.f, 0.f, 0.f, 0.f};
    #pragma unroll
    for (int s = 0; s < OUTER; ++s) {
        float4 t = ((const float4*)pgp)[((size_t)s * BB + b) * NN + n];
        pgf[0] += t.x; pgf[1] += t.y; pgf[2] += t.z; pgf[3] += t.w;
    }
    float4 g0v = ((const float4*)g0c)[(size_t)b * NN + n];
    float g0f[4] = {g0v.x, g0v.y, g0v.z, g0v.w};

    float pre[4];
    #pragma unroll
    for (int j = 0; j < 4; ++j) {
        float bj = 0.f;
        #pragma unroll
        for (int d = 0; d < 4; ++d) {
            float bp = (j < 2) ? bg[d * 4 + 2 + j] : bu[d * 2 + (j - 2)];
            bj += ed[d] * bp;
        }
        pre[j] = g0f[j] + rd * pgf[j] + bj;
    }
    float R0 = fsig(pre[0]);
    float R1 = fsig(pre[1]);
    float C0 = ftanh(pre[2]);
    float C1 = ftanh(pre[3]);
    float h0 = (1.f - R0) * C0;
    float h1 = (1.f - R1) * C1;
    float y = fmaxf(h0, 0.f) * lw[0] + fmaxf(h1, 0.f) * lw[1] + lb[0];
    out[(size_t)b * NN + n] = y;
}

// ---------------------------------------------------------------------------
extern "C" void kernel_launch(void* const* d_in, const int* in_sizes, int n_in,
                              void* d_out, int out_size, void* d_ws, size_t ws_size,
                              hipStream_t stream) {
    const float* x  = (const float*)d_in[0];
    const float* e  = (const float*)d_in[1];
    const float* wg = (const float*)d_in[2];
    const float* bg = (const float*)d_in[3];
    const float* wu = (const float*)d_in[4];
    const float* bu = (const float*)d_in[5];
    const float* lw = (const float*)d_in[6];
    const float* lb = (const float*)d_in[7];
    float* out = (float*)d_out;

    float*  wsf   = (float*)d_ws;
    float*  rsums = wsf + OFF_RSUM;
    float*  g0c   = wsf + OFF_G0C;
    float*  pgp   = wsf + OFF_PGP;
    ushort* gtf   = (ushort*)(wsf + OFF_GTF);

    hipLaunchKernelGGL(kg_g, dim3(22, 16), dim3(256), 0, stream, x, e, wg, wu, g0c, gtf);
    hipLaunchKernelGGL(kb_pg, dim3(44, OUTER), dim3(256), 0, stream, e, gtf, pgp, rsums);
    hipLaunchKernelGGL(ke_out, dim3(22, 16), dim3(256), 0, stream,
                       e, rsums, g0c, pgp, bg, bu, lw, lb, out);
}

// Round 10
// 128.555 us; speedup vs baseline: 1.2484x; 1.2484x over previous
//
#include <hip/hip_runtime.h>
#include <hip/hip_bf16.h>
#include <math.h>

// Problem constants (fixed by setup_inputs)
#define NN   5570
#define BB   16
#define CIN  35
#define MPAD 5632      // NN padded to 88*64
#define NCHUNK 176     // MPAD/32  (k-chunks of 32)
#define OUTER 11       // split-K slices (blockIdx.y); 16 chunks = 512 k each
#define CPS  16        // chunks per slice

// workspace layout (float offsets); total 5,060,608 floats ~= 20.2 MB
#define OFF_RSUM 0                          // [OUTER][MPAD] fp32 = 61952
#define OFF_G0C  61952                      // [BB][NN][4] fp32 = 356480
#define OFF_PGP  418432                     // [OUTER][BB][NN][4] fp32 = 3921280
#define OFF_GTF  4339712                    // gtf bf16 [NCHUNK][BB][64][8]

typedef __attribute__((ext_vector_type(8))) short  short8;
typedef __attribute__((ext_vector_type(4))) float  floatx4;

static __device__ inline ushort f2bf(float f) {
    union { __hip_bfloat16 h; ushort u; } cv;
    cv.h = __float2bfloat16(f);
    return cv.u;
}

// ---------------------------------------------------------------------------
// Kernel G: per (b, m):
//   a0[dj] = sum_c x[b,m,c]*w_k0[d,c,j];  g0c[b][m][j] = sum_d E[m,d]*a0[dj]
//   a1[dj] = sum_c x[b,m,c]*w_k1[d,c,j] -> gtf bf16 in MFMA-B-fragment order:
//       gtf[((ck*16 + b)*64 + quad*16 + dj)*8 + u],  m = ck*32 + quad*8 + u
// R10: 2 rows/thread, 128-thr blocks, SAME 256-row tiles (grid 22x16).
// kg_g is LDS-issue bound on wave-uniform wl broadcast reads (280 b128/wave
// per 64 rows; critical-CU makespan ~12.6us with 2 blocks on 96 CUs). Each
// wl float4 read now feeds 2 rows -> issues per row halve -> ~7us makespan.
// Per-row FMA order (c, then kd) unchanged -> bit-identical a0/a1. xs tail
// zero-filled so padding rows still yield a1=0 (kb_pg multiplies garbage
// B rows by score 0 -- must not be NaN). ls->gtf pack logic verbatim
// (write-out: 2 waves x 4 chunks instead of 4 x 2).
// ---------------------------------------------------------------------------
__global__ __launch_bounds__(128)
void kg_g(const float* __restrict__ x, const float* __restrict__ e,
          const float* __restrict__ wg, const float* __restrict__ wu,
          float* __restrict__ g0c, ushort* __restrict__ gtf) {
    __shared__ float xs[256 * CIN];
    __shared__ float wl[8 * CIN * 4];    // [(k*4+d)*35 + c]*4 + j
    __shared__ ushort ls[256 * 17];      // staged a1, row stride 17 (pad)
    int tid = threadIdx.x;               // 0..127
    int b   = blockIdx.y;
    int m0  = blockIdx.x * 256;

    for (int i = tid; i < 8 * CIN * 4; i += 128) {
        int j = i & 3, rest = i >> 2;
        int c = rest % CIN, kd = rest / CIN;
        int k = kd >> 2, d = kd & 3;
        float v;
        if (j < 2) v = wg[((d * 2 + k) * 37 + c) * 4 + 2 + j];
        else       v = wu[((d * 2 + k) * 37 + c) * 2 + (j - 2)];
        wl[i] = v;
    }
    int rows = NN - m0; if (rows > 256) rows = 256; if (rows < 0) rows = 0;
    const float* xsrc = x + ((size_t)b * NN + m0) * CIN;
    for (int i = tid; i < rows * CIN; i += 128) xs[i] = xsrc[i];
    // zero-fill tail rows so row-1 (tid+128) accumulators come out 0, not NaN
    for (int i = rows * CIN + tid; i < 256 * CIN; i += 128) xs[i] = 0.f;
    __syncthreads();

    float a0[2][16], a1[2][16];
    #pragma unroll
    for (int r = 0; r < 2; ++r)
        #pragma unroll
        for (int i = 0; i < 16; ++i) { a0[r][i] = 0.f; a1[r][i] = 0.f; }

    for (int c = 0; c < CIN; ++c) {
        float xa0 = xs[tid * CIN + c];
        float xa1 = xs[(tid + 128) * CIN + c];
        #pragma unroll
        for (int kd = 0; kd < 8; ++kd) {
            const float4 w = *(const float4*)&wl[(kd * CIN + c) * 4];  // 1 read, 2 rows
            const int d4 = (kd & 3) * 4;
            if (kd < 4) {
                a0[0][d4+0] += xa0*w.x; a0[0][d4+1] += xa0*w.y;
                a0[0][d4+2] += xa0*w.z; a0[0][d4+3] += xa0*w.w;
                a0[1][d4+0] += xa1*w.x; a0[1][d4+1] += xa1*w.y;
                a0[1][d4+2] += xa1*w.z; a0[1][d4+3] += xa1*w.w;
            } else {
                a1[0][d4+0] += xa0*w.x; a1[0][d4+1] += xa0*w.y;
                a1[0][d4+2] += xa0*w.z; a1[0][d4+3] += xa0*w.w;
                a1[1][d4+0] += xa1*w.x; a1[1][d4+1] += xa1*w.y;
                a1[1][d4+2] += xa1*w.z; a1[1][d4+3] += xa1*w.w;
            }
        }
    }

    #pragma unroll
    for (int r = 0; r < 2; ++r) {
        const int lm = tid + r * 128;
        const int m  = m0 + lm;
        if (m < NN) {
            // fold E-contraction for k=0 term: p0[j] = sum_d E[m,d]*a0[d*4+j]
            float4 em4 = ((const float4*)e)[m];
            float p0[4];
            #pragma unroll
            for (int j = 0; j < 4; ++j)
                p0[j] = em4.x*a0[r][j] + em4.y*a0[r][4+j]
                      + em4.z*a0[r][8+j] + em4.w*a0[r][12+j];
            ((float4*)g0c)[(size_t)b * NN + m] = make_float4(p0[0], p0[1], p0[2], p0[3]);
        }
        // stage a1 -> LDS [m_local][dj] (stride 17); a1=0 for padding rows
        #pragma unroll
        for (int dj = 0; dj < 16; ++dj) ls[lm * 17 + dj] = f2bf(a1[r][dj]);
    }
    __syncthreads();

    // coalesced write-out: wave w handles local chunks {4w .. 4w+3}
    const int wave = tid >> 6, lane = tid & 63;
    const int qo = lane >> 4, dj = lane & 15;
    #pragma unroll
    for (int i = 0; i < 4; ++i) {
        const int lc = wave * 4 + i;
        const int ck = blockIdx.x * 8 + lc;
        short8 v;
        #pragma unroll
        for (int u = 0; u < 8; ++u)
            v[u] = (short)ls[(lc * 32 + qo * 8 + u) * 17 + dj];
        *(short8*)&gtf[((size_t)(ck * 16 + b)) * 512 + lane * 8] = v;
    }
}

// ---------------------------------------------------------------------------
// Kernel B (fused score-gen + MFMA, LDS double-buffered B via global_load_lds):
//   PG contribution over slice s: sum_m exp(relu(E_n.E_m)) * G1[m][col]
//   rsums[s][n] = per-slice row sum of scores (no atomics)
// Block = 4 waves; wave w owns row-tile rt = bx*4+w, all 16 col-tiles.
// R6 (T4, m218, CONFIRMED best: 122.1us total): counted vmcnt + RAW
// s_barrier. Per step: issue chunk st+1 (4 gload_lds/wave) -> s_waitcnt
// vmcnt(4) (waits ONLY chunk st, FIFO-oldest; st+1 stays in flight ACROSS
// the barrier) -> compute -> raw s_barrier (no drain). Buffer safety: step
// st writes buf[(st+1)&1], last read in step st-1, sealed by the st-1
// end-barrier; vmcnt(4) covers the wave's own staged quarter; ds_read->MFMA
// lgkmcnt compiler-inserted.
// esl stored XOR-swizzled (slot = i ^ ((i>>3)&7)) - measured-neutral, kept.
// NOTE (R1): counter-fused final epilogue FAILED correctness cross-XCD.
// NOTE (R7): cross-XCD atomicAdd accumulation ALSO failed (absmax 0.58).
//            ONLY kernel-boundary plain-store dataflow is safe here.
// NOTE (R3/R8): 2-rowtile waves never beat this (fewer waves/CU; traffic x
//            concurrency trade is a wash: R8 42us @ 8 waves vs R6 38 @ 15).
// NOTE (R9): __launch_bounds__(256,3) SPILLED the 128-VGPR acc (VGPR=84,
//            WRITE_SIZE 75MB scratch) -> 78us. Never cap below acc size.
// NOTE (R4): B-frags direct from L2 regressed (87us). (R5): OUTER=22 with
//            drain barriers regressed (per-block overhead).
// ---------------------------------------------------------------------------
static __device__ inline void load_chunk(const ushort* __restrict__ gsrc,
                                         ushort* ldst, int tid, int wave) {
    #pragma unroll
    for (int i = 0; i < 4; ++i) {
        const ushort* g = gsrc + (size_t)(i * 256 + tid) * 8;
        ushort* l = ldst + (size_t)(i * 256 + wave * 64) * 8;  // wave-uniform base
        __builtin_amdgcn_global_load_lds(
            (const __attribute__((address_space(1))) unsigned int*)g,
            (__attribute__((address_space(3))) unsigned int*)l, 16, 0, 0);
    }
}

template <bool CHECK>
__device__ __forceinline__ void kb_main(const float4* __restrict__ esl,
                                        const ushort* __restrict__ gsl,
                                        ushort (*sbuf)[8192],
                                        const float4 en, int k0m,
                                        int tid, int wave, int lane, int quad,
                                        floatx4 (&acc)[16], float& rowsum) {
    #pragma unroll 2
    for (int st = 0; st < CPS; ++st) {
        // [A] issue next chunk, [B] wait ONLY for chunk st (counted, not 0)
        if (st + 1 < CPS) {
            load_chunk(gsl + (size_t)(st + 1) * 8192, sbuf[(st + 1) & 1], tid, wave);
            asm volatile("s_waitcnt vmcnt(4)" ::: "memory");
        } else {
            asm volatile("s_waitcnt vmcnt(0)" ::: "memory");
        }

        // scores for this step's A-fragment: lane holds A[rt*16+l15][quad*8+u]
        short8 af;
        const int stq = st * 32 + quad * 8;
        const int ux  = (st * 4 + quad) & 7;   // esl XOR-swizzle key
        #pragma unroll
        for (int u = 0; u < 8; ++u) {
            float4 em = esl[stq + (u ^ ux)];   // swizzled slot holds row stq+u
            float dt = en.x*em.x + en.y*em.y + en.z*em.z + en.w*em.w;
            float sv = __expf(fmaxf(dt, 0.f));
            if (CHECK && (k0m + stq + u >= NN)) sv = 0.f;
            rowsum += sv;
            af[u] = (short)f2bf(sv);
        }

        const ushort* bb = &sbuf[st & 1][lane * 8];
        #pragma unroll
        for (int ct = 0; ct < 16; ++ct) {
            short8 bf = *(const short8*)&bb[ct * 512];
            acc[ct] = __builtin_amdgcn_mfma_f32_16x16x32_bf16(af, bf, acc[ct], 0, 0, 0);
        }

        // [D] raw barrier, NO vmcnt drain: chunk st+1 stays in flight.
        // Seals buf[st&1] reads before step st+1 overwrites it.
        __builtin_amdgcn_s_barrier();
    }
}

__global__ __launch_bounds__(256, 4)
void kb_pg(const float* __restrict__ e, const ushort* __restrict__ gtf,
           float* __restrict__ pgp, float* __restrict__ rsums) {
    __shared__ ushort sbuf[2][8192];     // double-buffered B chunk, 32 KB
    __shared__ float4 esl[512];          // slice's E rows (XOR-swizzled), 8 KB
    const int tid  = threadIdx.x;
    const int wave = tid >> 6;
    const int lane = tid & 63;
    const int l15  = lane & 15;
    const int quad = lane >> 4;
    const int rt   = blockIdx.x * 4 + wave;
    const int s    = blockIdx.y;
    const int k0m  = s * (CPS * 32);     // first m of slice
    const float4* E4 = (const float4*)e;

    // stage slice E rows (swizzled: slot i^((i>>3)&7) holds row i) + first chunk
    for (int i = tid; i < 512; i += 256) {
        int m = k0m + i;
        esl[i ^ ((i >> 3) & 7)] = (m < NN) ? E4[m] : make_float4(0.f, 0.f, 0.f, 0.f);
    }
    const ushort* gsl = gtf + (size_t)s * CPS * 8192;
    load_chunk(gsl, sbuf[0], tid, wave);

    const int nr = rt * 16 + l15;
    const float4 en = E4[nr < NN ? nr : 0];

    floatx4 acc[16];
    #pragma unroll
    for (int i = 0; i < 16; ++i) acc[i] = (floatx4){0.f, 0.f, 0.f, 0.f};
    float rowsum = 0.f;

    __syncthreads();   // prologue sync: esl visible + chunk0 drained (once)

    if (k0m + CPS * 32 <= NN)
        kb_main<false>(esl, gsl, sbuf, en, k0m, tid, wave, lane, quad, acc, rowsum);
    else
        kb_main<true >(esl, gsl, sbuf, en, k0m, tid, wave, lane, quad, acc, rowsum);

    // rsums: row l15, partial per quad -> butterfly over quads, quad0 stores
    rowsum += __shfl_xor(rowsum, 16);
    rowsum += __shfl_xor(rowsum, 32);
    if (quad == 0) rsums[(size_t)s * MPAD + nr] = rowsum;   // nr < MPAD always

    // epilogue: acc[ct][j] = D[n = rt*16+quad*4+j][dj = l15]
    // contract dj = d*4+jj with E[n,d]: reduce over d via shfl_xor(4),(8)
    const int dsel = l15 >> 2, jj = l15 & 3;
    float end[4];
    #pragma unroll
    for (int j = 0; j < 4; ++j) {
        int n = rt * 16 + quad * 4 + j;
        end[j] = (n < NN) ? e[n * 4 + dsel] : 0.f;
    }
    #pragma unroll
    for (int ct = 0; ct < 16; ++ct) {
        #pragma unroll
        for (int j = 0; j < 4; ++j) {
            float v = end[j] * acc[ct][j];
            v += __shfl_xor(v, 4);
            v += __shfl_xor(v, 8);
            int n = rt * 16 + quad * 4 + j;
            if (l15 < 4 && n < NN)
                pgp[(((size_t)s * BB + ct) * NN + n) * 4 + jj] = v;
        }
    }
}

// ---------------------------------------------------------------------------
// Kernel E: tiny epilogue
// pre[j] = g0c[b][n][j] + (1/sum_s rsums[s][n]) * sum_s pgp[s][b][n][j]
//          + sum_d E[n,d]*bias[d][j]
// R=sigmoid(pre[0..1]), C=tanh(pre[2..3]), h=(1-R)*C, y = relu(h)@lin_w + lin_b
// ---------------------------------------------------------------------------
static __device__ inline float fsig(float x) {
    return 1.f / (1.f + __expf(-x));
}
static __device__ inline float ftanh(float x) {
    float t = __expf(fminf(2.f * x, 80.f));
    return (t - 1.f) / (t + 1.f);
}

__global__ __launch_bounds__(256)
void ke_out(const float* __restrict__ e, const float* __restrict__ rsums,
            const float* __restrict__ g0c, const float* __restrict__ pgp,
            const float* __restrict__ bg, const float* __restrict__ bu,
            const float* __restrict__ lw, const float* __restrict__ lb,
            float* __restrict__ out) {
    int n = blockIdx.x * 256 + threadIdx.x;
    int b = blockIdx.y;
    if (n >= NN) return;
    float4 ev = ((const float4*)e)[n];
    float ed[4] = {ev.x, ev.y, ev.z, ev.w};
    float den = 0.f;
    #pragma unroll
    for (int s = 0; s < OUTER; ++s) den += rsums[(size_t)s * MPAD + n];
    float rd = 1.f / den;

    float pgf[4] = {0.f, 0.f, 0.f, 0.f};
    #pragma unroll
    for (int s = 0; s < OUTER; ++s) {
        float4 t = ((const float4*)pgp)[((size_t)s * BB + b) * NN + n];
        pgf[0] += t.x; pgf[1] += t.y; pgf[2] += t.z; pgf[3] += t.w;
    }
    float4 g0v = ((const float4*)g0c)[(size_t)b * NN + n];
    float g0f[4] = {g0v.x, g0v.y, g0v.z, g0v.w};

    float pre[4];
    #pragma unroll
    for (int j = 0; j < 4; ++j) {
        float bj = 0.f;
        #pragma unroll
        for (int d = 0; d < 4; ++d) {
            float bp = (j < 2) ? bg[d * 4 + 2 + j] : bu[d * 2 + (j - 2)];
            bj += ed[d] * bp;
        }
        pre[j] = g0f[j] + rd * pgf[j] + bj;
    }
    float R0 = fsig(pre[0]);
    float R1 = fsig(pre[1]);
    float C0 = ftanh(pre[2]);
    float C1 = ftanh(pre[3]);
    float h0 = (1.f - R0) * C0;
    float h1 = (1.f - R1) * C1;
    float y = fmaxf(h0, 0.f) * lw[0] + fmaxf(h1, 0.f) * lw[1] + lb[0];
    out[(size_t)b * NN + n] = y;
}

// ---------------------------------------------------------------------------
extern "C" void kernel_launch(void* const* d_in, const int* in_sizes, int n_in,
                              void* d_out, int out_size, void* d_ws, size_t ws_size,
                              hipStream_t stream) {
    const float* x  = (const float*)d_in[0];
    const float* e  = (const float*)d_in[1];
    const float* wg = (const float*)d_in[2];
    const float* bg = (const float*)d_in[3];
    const float* wu = (const float*)d_in[4];
    const float* bu = (const float*)d_in[5];
    const float* lw = (const float*)d_in[6];
    const float* lb = (const float*)d_in[7];
    float* out = (float*)d_out;

    float*  wsf   = (float*)d_ws;
    float*  rsums = wsf + OFF_RSUM;
    float*  g0c   = wsf + OFF_G0C;
    float*  pgp   = wsf + OFF_PGP;
    ushort* gtf   = (ushort*)(wsf + OFF_GTF);

    hipLaunchKernelGGL(kg_g, dim3(22, 16), dim3(128), 0, stream, x, e, wg, wu, g0c, gtf);
    hipLaunchKernelGGL(kb_pg, dim3(88, OUTER), dim3(256), 0, stream, e, gtf, pgp, rsums);
    hipLaunchKernelGGL(ke_out, dim3(22, 16), dim3(256), 0, stream,
                       e, rsums, g0c, pgp, bg, bu, lw, lb, out);
}

// Round 11
// 123.720 us; speedup vs baseline: 1.2972x; 1.0391x over previous
//
#include <hip/hip_runtime.h>
#include <hip/hip_bf16.h>
#include <math.h>

// Problem constants (fixed by setup_inputs)
#define NN   5570
#define BB   16
#define CIN  35
#define MPAD 5632      // NN padded to 88*64
#define NCHUNK 176     // MPAD/32  (k-chunks of 32)
#define OUTER 11       // split-K slices (blockIdx.y); 16 chunks = 512 k each
#define CPS  16        // chunks per slice

// workspace layout (float offsets); total 5,060,608 floats ~= 20.2 MB
#define OFF_RSUM 0                          // [OUTER][MPAD] fp32 = 61952
#define OFF_G0C  61952                      // [BB][NN][4] fp32 = 356480
#define OFF_PGP  418432                     // [OUTER][BB][NN][4] fp32 = 3921280
#define OFF_GTF  4339712                    // gtf bf16 [NCHUNK][BB][64][8]

typedef __attribute__((ext_vector_type(8))) short  short8;
typedef __attribute__((ext_vector_type(4))) float  floatx4;

static __device__ inline ushort f2bf(float f) {
    union { __hip_bfloat16 h; ushort u; } cv;
    cv.h = __float2bfloat16(f);
    return cv.u;
}

// ---------------------------------------------------------------------------
// SESSION LEDGER (rounds 0-10; best = THIS configuration, 122.1us @ R6):
//  R6  WIN  (-3 vs R2): counted vmcnt(4) + raw s_barrier in kb_pg main loop
//           (T4/m218: never drain vmcnt to 0 in the loop).
//  R2  NEUT: esl XOR-swizzle (kept, zero cost).
//  R1  FAIL: intra-kernel cross-block epilogue via counter+threadfence ->
//            stale pgp/rsums cross-XCD (absmax 7.4e-2).
//  R7  FAIL: cross-XCD atomicAdd accumulation -> lost updates (absmax .58).
//            ONLY kernel-boundary plain-store dataflow is safe here.
//  R3/R8/R10 FAIL: every traffic-for-concurrency trade (2-rowtile waves,
//            2-row kg_g threads) regressed: fewer waves -> latency exposed.
//  R4  FAIL: B-frags direct from L2 (87us): raw L2 latency on MFMA path.
//  R5  FAIL: OUTER=22 with drain barriers: per-block overhead dominates.
//  R9  FAIL: __launch_bounds__(256,3) spilled 128-VGPR acc (VGPR=84,
//            75MB scratch writes). Never cap VGPR below acc footprint.
// Budget at 122us: 42 fill (harness, uncontrollable) + ~38 kb_pg (latency
// floor, no pipe >40%) + ~13 kg_g+ke_out + ~29 gaps/replay overhead.
// ---------------------------------------------------------------------------

// ---------------------------------------------------------------------------
// Kernel G: per (b, m):
//   a0[dj] = sum_c x[b,m,c]*w_k0[d,c,j];  g0c[b][m][j] = sum_d E[m,d]*a0[dj]
//   a1[dj] = sum_c x[b,m,c]*w_k1[d,c,j] -> gtf bf16 in MFMA-B-fragment order:
//       gtf[((ck*16 + b)*64 + quad*16 + dj)*8 + u],  m = ck*32 + quad*8 + u
// Writes go through an LDS transpose so global stores are coalesced short8.
// ---------------------------------------------------------------------------
__global__ __launch_bounds__(256)
void kg_g(const float* __restrict__ x, const float* __restrict__ e,
          const float* __restrict__ wg, const float* __restrict__ wu,
          float* __restrict__ g0c, ushort* __restrict__ gtf) {
    __shared__ float xs[256 * CIN];
    __shared__ float wl[8 * CIN * 4];    // [(k*4+d)*35 + c]*4 + j
    __shared__ ushort ls[256 * 17];      // staged a1, row stride 17 (pad)
    int tid = threadIdx.x;
    int b   = blockIdx.y;
    int m0  = blockIdx.x * 256;

    for (int i = tid; i < 8 * CIN * 4; i += 256) {
        int j = i & 3, rest = i >> 2;
        int c = rest % CIN, kd = rest / CIN;
        int k = kd >> 2, d = kd & 3;
        float v;
        if (j < 2) v = wg[((d * 2 + k) * 37 + c) * 4 + 2 + j];
        else       v = wu[((d * 2 + k) * 37 + c) * 2 + (j - 2)];
        wl[i] = v;
    }
    int rows = NN - m0; if (rows > 256) rows = 256; if (rows < 0) rows = 0;
    const float* xsrc = x + ((size_t)b * NN + m0) * CIN;
    for (int i = tid; i < rows * CIN; i += 256) xs[i] = xsrc[i];
    __syncthreads();

    int m = m0 + tid;
    float a1[16];
    #pragma unroll
    for (int i = 0; i < 16; ++i) a1[i] = 0.f;

    if (m < NN) {
        float a0[16];
        #pragma unroll
        for (int i = 0; i < 16; ++i) a0[i] = 0.f;
        for (int c = 0; c < CIN; ++c) {
            float xa = xs[tid * CIN + c];
            #pragma unroll
            for (int kd = 0; kd < 8; ++kd) {
                const float4 w = *(const float4*)&wl[(kd * CIN + c) * 4];
                const int d4 = (kd & 3) * 4;
                if (kd < 4) {
                    a0[d4+0] += xa*w.x; a0[d4+1] += xa*w.y;
                    a0[d4+2] += xa*w.z; a0[d4+3] += xa*w.w;
                } else {
                    a1[d4+0] += xa*w.x; a1[d4+1] += xa*w.y;
                    a1[d4+2] += xa*w.z; a1[d4+3] += xa*w.w;
                }
            }
        }
        // fold E-contraction for k=0 term: p0[j] = sum_d E[m,d]*a0[d*4+j]
        float4 em4 = ((const float4*)e)[m];
        float p0[4];
        #pragma unroll
        for (int j = 0; j < 4; ++j)
            p0[j] = em4.x*a0[j] + em4.y*a0[4+j] + em4.z*a0[8+j] + em4.w*a0[12+j];
        ((float4*)g0c)[(size_t)b * NN + m] = make_float4(p0[0], p0[1], p0[2], p0[3]);
    }

    // stage a1 -> LDS [m_local][dj] (stride 17)
    #pragma unroll
    for (int dj = 0; dj < 16; ++dj) ls[tid * 17 + dj] = f2bf(a1[dj]);
    __syncthreads();

    // coalesced write-out: wave w handles local chunks {2w, 2w+1}
    const int wave = tid >> 6, lane = tid & 63;
    const int qo = lane >> 4, dj = lane & 15;
    #pragma unroll
    for (int i = 0; i < 2; ++i) {
        const int lc = wave * 2 + i;
        const int ck = blockIdx.x * 8 + lc;
        short8 v;
        #pragma unroll
        for (int u = 0; u < 8; ++u)
            v[u] = (short)ls[(lc * 32 + qo * 8 + u) * 17 + dj];
        *(short8*)&gtf[((size_t)(ck * 16 + b)) * 512 + lane * 8] = v;
    }
}

// ---------------------------------------------------------------------------
// Kernel B (fused score-gen + MFMA, LDS double-buffered B via global_load_lds):
//   PG contribution over slice s: sum_m exp(relu(E_n.E_m)) * G1[m][col]
//   rsums[s][n] = per-slice row sum of scores (no atomics)
// Block = 4 waves; wave w owns row-tile rt = bx*4+w, all 16 col-tiles.
// R6 (T4, m218, CONFIRMED best): counted vmcnt + RAW s_barrier. Per step:
// issue chunk st+1 (4 gload_lds/wave) -> s_waitcnt vmcnt(4) (waits ONLY
// chunk st, FIFO-oldest; st+1 stays in flight ACROSS the barrier) ->
// compute -> raw s_barrier (no drain). Buffer safety: step st writes
// buf[(st+1)&1], last read in step st-1, sealed by the st-1 end-barrier;
// vmcnt(4) covers the wave's own staged quarter; ds_read->MFMA lgkmcnt
// compiler-inserted. Last step waits vmcnt(0).
// esl stored XOR-swizzled (slot = i ^ ((i>>3)&7)) - measured-neutral, kept.
// ---------------------------------------------------------------------------
static __device__ inline void load_chunk(const ushort* __restrict__ gsrc,
                                         ushort* ldst, int tid, int wave) {
    #pragma unroll
    for (int i = 0; i < 4; ++i) {
        const ushort* g = gsrc + (size_t)(i * 256 + tid) * 8;
        ushort* l = ldst + (size_t)(i * 256 + wave * 64) * 8;  // wave-uniform base
        __builtin_amdgcn_global_load_lds(
            (const __attribute__((address_space(1))) unsigned int*)g,
            (__attribute__((address_space(3))) unsigned int*)l, 16, 0, 0);
    }
}

template <bool CHECK>
__device__ __forceinline__ void kb_main(const float4* __restrict__ esl,
                                        const ushort* __restrict__ gsl,
                                        ushort (*sbuf)[8192],
                                        const float4 en, int k0m,
                                        int tid, int wave, int lane, int quad,
                                        floatx4 (&acc)[16], float& rowsum) {
    #pragma unroll 2
    for (int st = 0; st < CPS; ++st) {
        // [A] issue next chunk, [B] wait ONLY for chunk st (counted, not 0)
        if (st + 1 < CPS) {
            load_chunk(gsl + (size_t)(st + 1) * 8192, sbuf[(st + 1) & 1], tid, wave);
            asm volatile("s_waitcnt vmcnt(4)" ::: "memory");
        } else {
            asm volatile("s_waitcnt vmcnt(0)" ::: "memory");
        }

        // scores for this step's A-fragment: lane holds A[rt*16+l15][quad*8+u]
        short8 af;
        const int stq = st * 32 + quad * 8;
        const int ux  = (st * 4 + quad) & 7;   // esl XOR-swizzle key
        #pragma unroll
        for (int u = 0; u < 8; ++u) {
            float4 em = esl[stq + (u ^ ux)];   // swizzled slot holds row stq+u
            float dt = en.x*em.x + en.y*em.y + en.z*em.z + en.w*em.w;
            float sv = __expf(fmaxf(dt, 0.f));
            if (CHECK && (k0m + stq + u >= NN)) sv = 0.f;
            rowsum += sv;
            af[u] = (short)f2bf(sv);
        }

        const ushort* bb = &sbuf[st & 1][lane * 8];
        #pragma unroll
        for (int ct = 0; ct < 16; ++ct) {
            short8 bf = *(const short8*)&bb[ct * 512];
            acc[ct] = __builtin_amdgcn_mfma_f32_16x16x32_bf16(af, bf, acc[ct], 0, 0, 0);
        }

        // [D] raw barrier, NO vmcnt drain: chunk st+1 stays in flight.
        // Seals buf[st&1] reads before step st+1 overwrites it.
        __builtin_amdgcn_s_barrier();
    }
}

__global__ __launch_bounds__(256, 4)
void kb_pg(const float* __restrict__ e, const ushort* __restrict__ gtf,
           float* __restrict__ pgp, float* __restrict__ rsums) {
    __shared__ ushort sbuf[2][8192];     // double-buffered B chunk, 32 KB
    __shared__ float4 esl[512];          // slice's E rows (XOR-swizzled), 8 KB
    const int tid  = threadIdx.x;
    const int wave = tid >> 6;
    const int lane = tid & 63;
    const int l15  = lane & 15;
    const int quad = lane >> 4;
    const int rt   = blockIdx.x * 4 + wave;
    const int s    = blockIdx.y;
    const int k0m  = s * (CPS * 32);     // first m of slice
    const float4* E4 = (const float4*)e;

    // stage slice E rows (swizzled: slot i^((i>>3)&7) holds row i) + first chunk
    for (int i = tid; i < 512; i += 256) {
        int m = k0m + i;
        esl[i ^ ((i >> 3) & 7)] = (m < NN) ? E4[m] : make_float4(0.f, 0.f, 0.f, 0.f);
    }
    const ushort* gsl = gtf + (size_t)s * CPS * 8192;
    load_chunk(gsl, sbuf[0], tid, wave);

    const int nr = rt * 16 + l15;
    const float4 en = E4[nr < NN ? nr : 0];

    floatx4 acc[16];
    #pragma unroll
    for (int i = 0; i < 16; ++i) acc[i] = (floatx4){0.f, 0.f, 0.f, 0.f};
    float rowsum = 0.f;

    __syncthreads();   // prologue sync: esl visible + chunk0 drained (once)

    if (k0m + CPS * 32 <= NN)
        kb_main<false>(esl, gsl, sbuf, en, k0m, tid, wave, lane, quad, acc, rowsum);
    else
        kb_main<true >(esl, gsl, sbuf, en, k0m, tid, wave, lane, quad, acc, rowsum);

    // rsums: row l15, partial per quad -> butterfly over quads, quad0 stores
    rowsum += __shfl_xor(rowsum, 16);
    rowsum += __shfl_xor(rowsum, 32);
    if (quad == 0) rsums[(size_t)s * MPAD + nr] = rowsum;   // nr < MPAD always

    // epilogue: acc[ct][j] = D[n = rt*16+quad*4+j][dj = l15]
    // contract dj = d*4+jj with E[n,d]: reduce over d via shfl_xor(4),(8)
    const int dsel = l15 >> 2, jj = l15 & 3;
    float end[4];
    #pragma unroll
    for (int j = 0; j < 4; ++j) {
        int n = rt * 16 + quad * 4 + j;
        end[j] = (n < NN) ? e[n * 4 + dsel] : 0.f;
    }
    #pragma unroll
    for (int ct = 0; ct < 16; ++ct) {
        #pragma unroll
        for (int j = 0; j < 4; ++j) {
            float v = end[j] * acc[ct][j];
            v += __shfl_xor(v, 4);
            v += __shfl_xor(v, 8);
            int n = rt * 16 + quad * 4 + j;
            if (l15 < 4 && n < NN)
                pgp[(((size_t)s * BB + ct) * NN + n) * 4 + jj] = v;
        }
    }
}

// ---------------------------------------------------------------------------
// Kernel E: tiny epilogue
// pre[j] = g0c[b][n][j] + (1/sum_s rsums[s][n]) * sum_s pgp[s][b][n][j]
//          + sum_d E[n,d]*bias[d][j]
// R=sigmoid(pre[0..1]), C=tanh(pre[2..3]), h=(1-R)*C, y = relu(h)@lin_w + lin_b
// ---------------------------------------------------------------------------
static __device__ inline float fsig(float x) {
    return 1.f / (1.f + __expf(-x));
}
static __device__ inline float ftanh(float x) {
    float t = __expf(fminf(2.f * x, 80.f));
    return (t - 1.f) / (t + 1.f);
}

__global__ __launch_bounds__(256)
void ke_out(const float* __restrict__ e, const float* __restrict__ rsums,
            const float* __restrict__ g0c, const float* __restrict__ pgp,
            const float* __restrict__ bg, const float* __restrict__ bu,
            const float* __restrict__ lw, const float* __restrict__ lb,
            float* __restrict__ out) {
    int n = blockIdx.x * 256 + threadIdx.x;
    int b = blockIdx.y;
    if (n >= NN) return;
    float4 ev = ((const float4*)e)[n];
    float ed[4] = {ev.x, ev.y, ev.z, ev.w};
    float den = 0.f;
    #pragma unroll
    for (int s = 0; s < OUTER; ++s) den += rsums[(size_t)s * MPAD + n];
    float rd = 1.f / den;

    float pgf[4] = {0.f, 0.f, 0.f, 0.f};
    #pragma unroll
    for (int s = 0; s < OUTER; ++s) {
        float4 t = ((const float4*)pgp)[((size_t)s * BB + b) * NN + n];
        pgf[0] += t.x; pgf[1] += t.y; pgf[2] += t.z; pgf[3] += t.w;
    }
    float4 g0v = ((const float4*)g0c)[(size_t)b * NN + n];
    float g0f[4] = {g0v.x, g0v.y, g0v.z, g0v.w};

    float pre[4];
    #pragma unroll
    for (int j = 0; j < 4; ++j) {
        float bj = 0.f;
        #pragma unroll
        for (int d = 0; d < 4; ++d) {
            float bp = (j < 2) ? bg[d * 4 + 2 + j] : bu[d * 2 + (j - 2)];
            bj += ed[d] * bp;
        }
        pre[j] = g0f[j] + rd * pgf[j] + bj;
    }
    float R0 = fsig(pre[0]);
    float R1 = fsig(pre[1]);
    float C0 = ftanh(pre[2]);
    float C1 = ftanh(pre[3]);
    float h0 = (1.f - R0) * C0;
    float h1 = (1.f - R1) * C1;
    float y = fmaxf(h0, 0.f) * lw[0] + fmaxf(h1, 0.f) * lw[1] + lb[0];
    out[(size_t)b * NN + n] = y;
}

// ---------------------------------------------------------------------------
extern "C" void kernel_launch(void* const* d_in, const int* in_sizes, int n_in,
                              void* d_out, int out_size, void* d_ws, size_t ws_size,
                              hipStream_t stream) {
    const float* x  = (const float*)d_in[0];
    const float* e  = (const float*)d_in[1];
    const float* wg = (const float*)d_in[2];
    const float* bg = (const float*)d_in[3];
    const float* wu = (const float*)d_in[4];
    const float* bu = (const float*)d_in[5];
    const float* lw = (const float*)d_in[6];
    const float* lb = (const float*)d_in[7];
    float* out = (float*)d_out;

    float*  wsf   = (float*)d_ws;
    float*  rsums = wsf + OFF_RSUM;
    float*  g0c   = wsf + OFF_G0C;
    float*  pgp   = wsf + OFF_PGP;
    ushort* gtf   = (ushort*)(wsf + OFF_GTF);

    hipLaunchKernelGGL(kg_g, dim3(22, 16), dim3(256), 0, stream, x, e, wg, wu, g0c, gtf);
    hipLaunchKernelGGL(kb_pg, dim3(88, OUTER), dim3(256), 0, stream, e, gtf, pgp, rsums);
    hipLaunchKernelGGL(ke_out, dim3(22, 16), dim3(256), 0, stream,
                       e, rsums, g0c, pgp, bg, bu, lw, lb, out);
}